// Round 2
// baseline (3778.405 us; speedup 1.0000x reference)
//
#include <hip/hip_runtime.h>
#include <hip/hip_bf16.h>

// Problem constants: B=64, T=2048, IN_F=128, H1=OUT_F=64, 4H=256
#define BB 64
#define TT 2048
#define INF 128
#define HH 64
#define GG 256  // 4*H

// ---------------------------------------------------------------------------
// Kernel 1: xg1[m][n] = X[m,:] . W_ih1[n,:] + b_ih1[n] + b_hh1[n]
// M=131072, N=256, K=128.
// Design: full W^T staged in LDS as Ws[k][n] (128 KB). Each thread owns ONE
// X row in 128 VGPRs (K fully unrolled -> constant reg indices). All W reads
// are same-address-across-wave broadcasts (conflict-free). Staging writes are
// bank = lane%32 -> conflict-free. 512 blocks, 1 block/CU, 2 rounds.
// ---------------------------------------------------------------------------
__global__ __launch_bounds__(256, 1) void xgemm(const float* __restrict__ X,
                                                const float* __restrict__ W,
                                                const float* __restrict__ bi,
                                                const float* __restrict__ bh,
                                                float* __restrict__ XG) {
  __shared__ __align__(16) float Ws[INF * GG];  // [k][n], 128 KB
  __shared__ __align__(16) float bsum[GG];      // 1 KB
  const int tid = threadIdx.x;
  const long m = (long)blockIdx.x * 256 + tid;  // this thread's X row

  // Load my X row into registers first (latency overlaps W staging).
  float4 xr[32];
  {
    const float4* Xg = (const float4*)(X + m * INF);
#pragma unroll
    for (int i = 0; i < 32; ++i) xr[i] = Xg[i];
  }

  // Stage W transposed: thread tid handles W row n=tid (all K).
  // Write addr = (4j+jj)*256 + tid -> bank = tid%32 -> conflict-free.
  {
    const float4* Wg = (const float4*)W;  // W[n][k] row-major, f4 idx = n*32+k4
#pragma unroll
    for (int j = 0; j < 32; ++j) {
      float4 w = Wg[tid * 32 + j];
      Ws[(4 * j + 0) * GG + tid] = w.x;
      Ws[(4 * j + 1) * GG + tid] = w.y;
      Ws[(4 * j + 2) * GG + tid] = w.z;
      Ws[(4 * j + 3) * GG + tid] = w.w;
    }
    bsum[tid] = bi[tid] + bh[tid];
  }
  __syncthreads();

  // 16 n-iterations of 16 outputs (4 float4 accumulators).
  for (int n2 = 0; n2 < 16; ++n2) {
    const float* wbase = &Ws[n2 * 16];
    float4 a0 = *(const float4*)&bsum[n2 * 16 + 0];
    float4 a1 = *(const float4*)&bsum[n2 * 16 + 4];
    float4 a2 = *(const float4*)&bsum[n2 * 16 + 8];
    float4 a3 = *(const float4*)&bsum[n2 * 16 + 12];
#pragma unroll
    for (int k = 0; k < INF; ++k) {
      float4 w0 = *(const float4*)&wbase[k * GG + 0];   // broadcast reads
      float4 w1 = *(const float4*)&wbase[k * GG + 4];
      float4 w2 = *(const float4*)&wbase[k * GG + 8];
      float4 w3 = *(const float4*)&wbase[k * GG + 12];
      const float4 x4 = xr[k >> 2];
      const float xk = (k & 3) == 0 ? x4.x : (k & 3) == 1 ? x4.y : (k & 3) == 2 ? x4.z : x4.w;
      a0.x += xk * w0.x; a0.y += xk * w0.y; a0.z += xk * w0.z; a0.w += xk * w0.w;
      a1.x += xk * w1.x; a1.y += xk * w1.y; a1.z += xk * w1.z; a1.w += xk * w1.w;
      a2.x += xk * w2.x; a2.y += xk * w2.y; a2.z += xk * w2.z; a2.w += xk * w2.w;
      a3.x += xk * w3.x; a3.y += xk * w3.y; a3.z += xk * w3.z; a3.w += xk * w3.w;
    }
    float4* O = (float4*)&XG[m * GG + n2 * 16];
    O[0] = a0; O[1] = a1; O[2] = a2; O[3] = a3;
  }
}

// ---------------------------------------------------------------------------
// Kernel 2: fused 2-layer LSTM, software-pipelined with 1-step layer skew.
// 64 blocks x 256 threads. Thread g owns gate-row g of layer1 AND layer2;
// weight rows live in native float4[16] arrays (SROA -> VGPRs, no punning).
// Per iteration: Phase A (all threads): g1(s) and g2(s-1), 192 FMAs in 12
// independent chains; barrier; Phase B: wave0 does layer-1 update while
// wave1 does layer-2 update + output store (parallel SIMDs); barrier.
// ---------------------------------------------------------------------------
__device__ __forceinline__ float sigm(float x) { return 1.0f / (1.0f + __expf(-x)); }
__device__ __forceinline__ float tanh_f(float x) {
  float e = __expf(2.0f * x);
  return 1.0f - 2.0f / (e + 1.0f);
}

__global__ __launch_bounds__(256, 1) void lstm2(const float* __restrict__ XG,
                                                const float* __restrict__ Whh1,
                                                const float* __restrict__ Wih2,
                                                const float* __restrict__ Whh2,
                                                const float* __restrict__ bi2,
                                                const float* __restrict__ bh2,
                                                const float* __restrict__ m1g,
                                                const float* __restrict__ m2g,
                                                float* __restrict__ out) {
  const int b = blockIdx.x, g = threadIdx.x;
  const int lane = g & 63;
  __shared__ __align__(16) float h1s[HH];
  __shared__ __align__(16) float x2s[HH];
  __shared__ __align__(16) float h2s[HH];
  __shared__ __align__(16) float g1s[GG];
  __shared__ __align__(16) float g2s[GG];

  // Weight rows in registers — native float4 arrays, constant indices only.
  float4 w1[16], wi2[16], wh2[16];
  {
    const float4* p1 = (const float4*)(Whh1 + (long)g * HH);
    const float4* p2 = (const float4*)(Wih2 + (long)g * HH);
    const float4* p3 = (const float4*)(Whh2 + (long)g * HH);
#pragma unroll
    for (int i = 0; i < 16; ++i) { w1[i] = p1[i]; wi2[i] = p2[i]; wh2[i] = p3[i]; }
  }
  const float bias2 = bi2[g] + bh2[g];

  float c1 = 0.f, c2 = 0.f, m1 = 0.f, m2 = 0.f;
  if (g < HH) {
    m1 = m1g[b * HH + g];
  } else if (g < 2 * HH) {
    m2 = m2g[b * HH + lane];
    h2s[lane] = 0.f;  // h2(-1) = 0, read by first dot2
  }

  const float* xg = XG + (size_t)b * TT * GG;
  float* ob = out + (size_t)b * TT * HH;

  float xg_cur = xg[g];           // xg(0)
  float xg_n1 = xg[GG + g];       // xg(1)

  // ---- prologue s=0: g1(0) = xg(0) (h1(-1)=0, no dot), update1 only ----
  g1s[g] = xg_cur;
  __syncthreads();
  if (g < HH) {
    float gi = g1s[g], gf = g1s[HH + g], gc = g1s[2 * HH + g], go = g1s[3 * HH + g];
    (void)gf;  // c1 prev is 0
    c1 = sigm(gi) * tanh_f(gc);
    float h1 = sigm(go) * tanh_f(c1);
    h1s[g] = h1;
    x2s[g] = h1 * m1;
  }
  __syncthreads();
  xg_cur = xg_n1;
  xg_n1 = xg[2 * GG + g];

  // ---- main loop s = 1 .. TT-1 ----
  for (int s = 1; s < TT; ++s) {
    // prefetch xg(s+2) (clamped; latency hidden under two phases)
    int pf = s + 2 < TT ? s + 2 : TT - 1;
    float xg_n2 = xg[(size_t)pf * GG + g];

    // Phase A: g1(s) = xg(s) + h1(s-1).w1 ; g2(s-1) = b2 + x2(s-1).wi2 + h2(s-2).wh2
    float4 a1 = {xg_cur, 0.f, 0.f, 0.f};
    float4 ax = {bias2, 0.f, 0.f, 0.f};
    float4 ah = {0.f, 0.f, 0.f, 0.f};
#pragma unroll
    for (int k = 0; k < 16; ++k) {
      float4 h4 = ((const float4*)h1s)[k];   // all-lane broadcast reads
      float4 x4 = ((const float4*)x2s)[k];
      float4 p4 = ((const float4*)h2s)[k];
      a1.x += h4.x * w1[k].x; a1.y += h4.y * w1[k].y; a1.z += h4.z * w1[k].z; a1.w += h4.w * w1[k].w;
      ax.x += x4.x * wi2[k].x; ax.y += x4.y * wi2[k].y; ax.z += x4.z * wi2[k].z; ax.w += x4.w * wi2[k].w;
      ah.x += p4.x * wh2[k].x; ah.y += p4.y * wh2[k].y; ah.z += p4.z * wh2[k].z; ah.w += p4.w * wh2[k].w;
    }
    g1s[g] = (a1.x + a1.y) + (a1.z + a1.w);
    g2s[g] = ((ax.x + ax.y) + (ax.z + ax.w)) + ((ah.x + ah.y) + (ah.z + ah.w));
    __syncthreads();

    // Phase B: wave0 -> layer1 update(s); wave1 -> layer2 update(s-1) + store
    if (g < HH) {
      float gi = g1s[g], gf = g1s[HH + g], gc = g1s[2 * HH + g], go = g1s[3 * HH + g];
      c1 = sigm(gf) * c1 + sigm(gi) * tanh_f(gc);
      float h1 = sigm(go) * tanh_f(c1);
      h1s[g] = h1;
      x2s[g] = h1 * m1;
    } else if (g < 2 * HH) {
      float gi = g2s[lane], gf = g2s[HH + lane], gc = g2s[2 * HH + lane], go = g2s[3 * HH + lane];
      c2 = sigm(gf) * c2 + sigm(gi) * tanh_f(gc);
      float h2 = sigm(go) * tanh_f(c2);
      h2s[lane] = h2;
      ob[(size_t)(s - 1) * HH + lane] = fmaxf(h2 * m2, 0.f);
    }
    __syncthreads();

    xg_cur = xg_n1;
    xg_n1 = xg_n2;
  }

  // ---- epilogue s=TT: g2(TT-1) + update2 only ----
  {
    float4 ax = {bias2, 0.f, 0.f, 0.f};
    float4 ah = {0.f, 0.f, 0.f, 0.f};
#pragma unroll
    for (int k = 0; k < 16; ++k) {
      float4 x4 = ((const float4*)x2s)[k];
      float4 p4 = ((const float4*)h2s)[k];
      ax.x += x4.x * wi2[k].x; ax.y += x4.y * wi2[k].y; ax.z += x4.z * wi2[k].z; ax.w += x4.w * wi2[k].w;
      ah.x += p4.x * wh2[k].x; ah.y += p4.y * wh2[k].y; ah.z += p4.z * wh2[k].z; ah.w += p4.w * wh2[k].w;
    }
    g2s[g] = ((ax.x + ax.y) + (ax.z + ax.w)) + ((ah.x + ah.y) + (ah.z + ah.w));
    __syncthreads();
    if (g >= HH && g < 2 * HH) {
      float gi = g2s[lane], gf = g2s[HH + lane], gc = g2s[2 * HH + lane], go = g2s[3 * HH + lane];
      c2 = sigm(gf) * c2 + sigm(gi) * tanh_f(gc);
      float h2 = sigm(go) * tanh_f(c2);
      ob[(size_t)(TT - 1) * HH + lane] = fmaxf(h2 * m2, 0.f);
    }
  }
}

extern "C" void kernel_launch(void* const* d_in, const int* in_sizes, int n_in,
                              void* d_out, int out_size, void* d_ws, size_t ws_size,
                              hipStream_t stream) {
  (void)in_sizes; (void)n_in; (void)out_size; (void)ws_size;
  const float* x     = (const float*)d_in[0];
  const float* W_ih1 = (const float*)d_in[1];
  const float* W_hh1 = (const float*)d_in[2];
  const float* b_ih1 = (const float*)d_in[3];
  const float* b_hh1 = (const float*)d_in[4];
  const float* W_ih2 = (const float*)d_in[5];
  const float* W_hh2 = (const float*)d_in[6];
  const float* b_ih2 = (const float*)d_in[7];
  const float* b_hh2 = (const float*)d_in[8];
  const float* mask1 = (const float*)d_in[9];
  const float* mask2 = (const float*)d_in[10];
  float* out = (float*)d_out;

  float* xg1 = (float*)d_ws;  // B*T*4H fp32 = 134,217,728 bytes

  xgemm<<<dim3(BB * TT / 256), dim3(256), 0, stream>>>(x, W_ih1, b_ih1, b_hh1, xg1);
  lstm2<<<dim3(BB), dim3(256), 0, stream>>>(xg1, W_hh1, W_ih2, W_hh2, b_ih2, b_hh2,
                                            mask1, mask2, out);
}

// Round 3
// 2781.318 us; speedup vs baseline: 1.3585x; 1.3585x over previous
//
#include <hip/hip_runtime.h>
#include <hip/hip_bf16.h>

// Problem constants: B=64, T=2048, IN_F=128, H1=OUT_F=64, 4H=256
#define BB 64
#define TT 2048
#define INF 128
#define HH 64
#define GG 256  // 4*H

__device__ __forceinline__ float sigm(float x) { return 1.0f / (1.0f + __expf(-x)); }
__device__ __forceinline__ float tanh_f(float x) {
  float e = __expf(2.0f * x);
  return 1.0f - 2.0f / (e + 1.0f);
}
// Wave-uniform broadcast of lane l's value via v_readlane (SGPR path, no LDS).
__device__ __forceinline__ float bcast(float v, int l) {
  return __uint_as_float(__builtin_amdgcn_readlane(__float_as_uint(v), l));
}

// ---------------------------------------------------------------------------
// Kernel 1: xg1[m][n] = X[m,:].W_ih1[n,:] + b_ih1[n] + b_hh1[n]
// M=131072, N=256, K=128. No LDS, no barriers: thread t owns W rows {t,128+t}
// in 256 VGPRs; x row lane-distributed (float2/lane), broadcast via readlane.
// 512 blocks x 128 threads (2 waves) = 1024 waves = 1 wave/SIMD chip-wide.
// ---------------------------------------------------------------------------
__global__ __launch_bounds__(128, 1) void xgemm(const float* __restrict__ X,
                                                const float* __restrict__ W,
                                                const float* __restrict__ bi,
                                                const float* __restrict__ bh,
                                                float* __restrict__ XG) {
  const int t = threadIdx.x;            // 0..127
  const int lane = t & 63;
  const long m0 = (long)blockIdx.x * 256;

  // Weight rows t and 128+t, constant-index scalar arrays -> SROA -> VGPRs.
  float w0[INF], w1[INF];
  {
    const float4* Wp = (const float4*)W;
#pragma unroll
    for (int i = 0; i < 32; ++i) {
      float4 a = Wp[t * 32 + i];
      w0[4 * i] = a.x; w0[4 * i + 1] = a.y; w0[4 * i + 2] = a.z; w0[4 * i + 3] = a.w;
      float4 b = Wp[(128 + t) * 32 + i];
      w1[4 * i] = b.x; w1[4 * i + 1] = b.y; w1[4 * i + 2] = b.z; w1[4 * i + 3] = b.w;
    }
  }
  const float bias0 = bi[t] + bh[t];
  const float bias1 = bi[128 + t] + bh[128 + t];

  const float2* Xp = (const float2*)X;  // x[m] float2-distributed: lane l holds k=2l,2l+1
  float2 cur = Xp[(size_t)m0 * 64 + lane];
  float2 nx1 = Xp[(size_t)(m0 + 1) * 64 + lane];

  for (int mi = 0; mi < 256; ++mi) {
    const long m = m0 + mi;
    float2 nx2 = make_float2(0.f, 0.f);
    if (mi + 2 < 256) nx2 = Xp[(size_t)(m + 2) * 64 + lane];

    float a0e = bias0, a0o = 0.f, a1e = bias1, a1o = 0.f;  // 4 indep chains
#pragma unroll
    for (int l = 0; l < 64; ++l) {
      float xa = bcast(cur.x, l);       // k = 2l
      float xb = bcast(cur.y, l);       // k = 2l+1
      a0e = fmaf(xa, w0[2 * l], a0e);
      a0o = fmaf(xb, w0[2 * l + 1], a0o);
      a1e = fmaf(xa, w1[2 * l], a1e);
      a1o = fmaf(xb, w1[2 * l + 1], a1o);
    }
    XG[(size_t)m * GG + t] = a0e + a0o;
    XG[(size_t)m * GG + 128 + t] = a1e + a1o;
    cur = nx1; nx1 = nx2;
  }
}

// ---------------------------------------------------------------------------
// Kernel 2: barrier-free wave-specialized LSTM pipeline. 64 blocks x 256 thr.
//   W0: layer-1. h1/c1 lane-distributed in registers; W_hh1 rows
//       {lane,64+lane,128+lane,192+lane} in 256 VGPRs; h broadcast via
//       readlane. Publishes x2 = h1*mask1 to a depth-4 LDS ring.
//   W1: a2x = b2 + Wih2 . x2  (256 VGPRs of Wih2), publishes to ring.
//   W2: a2h = Whh2 . h2 (own state), g2 = a2x + a2h, cell update, relu-store.
//   W3: exits (weights don't fit a 4th useful stage).
// Sync: monotonic LDS step counters, volatile spin + lgkmcnt(0) before
// publish. NO __syncthreads in the loop -> no vmcnt(0) drains; xg prefetch
// and output stores stay in flight.
// ---------------------------------------------------------------------------
__global__ __launch_bounds__(256, 1) void lstm2(const float* __restrict__ XG,
                                                const float* __restrict__ Whh1,
                                                const float* __restrict__ Wih2,
                                                const float* __restrict__ Whh2,
                                                const float* __restrict__ bi2,
                                                const float* __restrict__ bh2,
                                                const float* __restrict__ m1g,
                                                const float* __restrict__ m2g,
                                                float* __restrict__ out) {
  const int b = blockIdx.x;
  const int wid = threadIdx.x >> 6;
  const int lane = threadIdx.x & 63;

  __shared__ int f_w0, f_w1, f_w2;                  // steps completed per stage
  __shared__ __align__(16) float x2buf[4][HH];      // W0 -> W1 ring
  __shared__ __align__(16) float a2xbuf[4][GG];     // W1 -> W2 ring

  if (threadIdx.x == 0) { f_w0 = 0; f_w1 = 0; f_w2 = 0; }
  __syncthreads();  // one-time; flags visible before any spin
  if (wid == 3) return;

#define WAIT_GE(flag, tgt)                                   \
  do {                                                       \
    while (*(volatile int*)&(flag) < (tgt)) {}               \
    asm volatile("" ::: "memory");                           \
  } while (0)
#define PUBLISH(flag, val)                                   \
  do {                                                       \
    asm volatile("s_waitcnt lgkmcnt(0)" ::: "memory");       \
    if (lane == 0) *(volatile int*)&(flag) = (val);          \
  } while (0)

  if (wid == 0) {
    // ---- stage 0: layer 1 ----
    float wi[HH], wf[HH], wg[HH], wo[HH];
    {
      const float4* p = (const float4*)Whh1;
#pragma unroll
      for (int i = 0; i < 16; ++i) {
        float4 a = p[lane * 16 + i];
        wi[4 * i] = a.x; wi[4 * i + 1] = a.y; wi[4 * i + 2] = a.z; wi[4 * i + 3] = a.w;
        float4 c = p[(64 + lane) * 16 + i];
        wf[4 * i] = c.x; wf[4 * i + 1] = c.y; wf[4 * i + 2] = c.z; wf[4 * i + 3] = c.w;
        float4 d = p[(128 + lane) * 16 + i];
        wg[4 * i] = d.x; wg[4 * i + 1] = d.y; wg[4 * i + 2] = d.z; wg[4 * i + 3] = d.w;
        float4 e = p[(192 + lane) * 16 + i];
        wo[4 * i] = e.x; wo[4 * i + 1] = e.y; wo[4 * i + 2] = e.z; wo[4 * i + 3] = e.w;
      }
    }
    const float m1 = m1g[b * HH + lane];
    const float* xgp = XG + (size_t)b * TT * GG;

    float cur[4], nx1[4], nx2[4];
#pragma unroll
    for (int j = 0; j < 4; ++j) cur[j] = xgp[64 * j + lane];
#pragma unroll
    for (int j = 0; j < 4; ++j) nx1[j] = xgp[GG + 64 * j + lane];

    float h1 = 0.f, c1 = 0.f;
    for (int s = 0; s < TT; ++s) {
#pragma unroll
      for (int j = 0; j < 4; ++j)
        nx2[j] = (s + 2 < TT) ? xgp[(size_t)(s + 2) * GG + 64 * j + lane] : 0.f;

      float ai = cur[0], af = cur[1], ag = cur[2], ao = cur[3];
#pragma unroll
      for (int k = 0; k < HH; ++k) {
        float hk = bcast(h1, k);
        ai = fmaf(hk, wi[k], ai);
        af = fmaf(hk, wf[k], af);
        ag = fmaf(hk, wg[k], ag);
        ao = fmaf(hk, wo[k], ao);
      }
      c1 = sigm(af) * c1 + sigm(ai) * tanh_f(ag);
      h1 = sigm(ao) * tanh_f(c1);

      WAIT_GE(f_w1, s - 3);                 // ring slot free?
      x2buf[s & 3][lane] = h1 * m1;
      PUBLISH(f_w0, s + 1);

      cur[0] = nx1[0]; cur[1] = nx1[1]; cur[2] = nx1[2]; cur[3] = nx1[3];
      nx1[0] = nx2[0]; nx1[1] = nx2[1]; nx1[2] = nx2[2]; nx1[3] = nx2[3];
    }
  } else if (wid == 1) {
    // ---- stage 1: layer-2 input dot ----
    float wi[HH], wf[HH], wg[HH], wo[HH];
    {
      const float4* p = (const float4*)Wih2;
#pragma unroll
      for (int i = 0; i < 16; ++i) {
        float4 a = p[lane * 16 + i];
        wi[4 * i] = a.x; wi[4 * i + 1] = a.y; wi[4 * i + 2] = a.z; wi[4 * i + 3] = a.w;
        float4 c = p[(64 + lane) * 16 + i];
        wf[4 * i] = c.x; wf[4 * i + 1] = c.y; wf[4 * i + 2] = c.z; wf[4 * i + 3] = c.w;
        float4 d = p[(128 + lane) * 16 + i];
        wg[4 * i] = d.x; wg[4 * i + 1] = d.y; wg[4 * i + 2] = d.z; wg[4 * i + 3] = d.w;
        float4 e = p[(192 + lane) * 16 + i];
        wo[4 * i] = e.x; wo[4 * i + 1] = e.y; wo[4 * i + 2] = e.z; wo[4 * i + 3] = e.w;
      }
    }
    const float bi_i = bi2[lane] + bh2[lane];
    const float bi_f = bi2[64 + lane] + bh2[64 + lane];
    const float bi_g = bi2[128 + lane] + bh2[128 + lane];
    const float bi_o = bi2[192 + lane] + bh2[192 + lane];

    for (int s = 0; s < TT; ++s) {
      WAIT_GE(f_w0, s + 1);
      float x2 = x2buf[s & 3][lane];

      float ai = bi_i, af = bi_f, ag = bi_g, ao = bi_o;
#pragma unroll
      for (int k = 0; k < HH; ++k) {
        float xk = bcast(x2, k);
        ai = fmaf(xk, wi[k], ai);
        af = fmaf(xk, wf[k], af);
        ag = fmaf(xk, wg[k], ag);
        ao = fmaf(xk, wo[k], ao);
      }
      WAIT_GE(f_w2, s - 3);                 // ring slot free?
      a2xbuf[s & 3][lane] = ai;
      a2xbuf[s & 3][64 + lane] = af;
      a2xbuf[s & 3][128 + lane] = ag;
      a2xbuf[s & 3][192 + lane] = ao;
      PUBLISH(f_w1, s + 1);
    }
  } else {
    // ---- stage 2: layer-2 recurrent dot + update + store ----
    float wi[HH], wf[HH], wg[HH], wo[HH];
    {
      const float4* p = (const float4*)Whh2;
#pragma unroll
      for (int i = 0; i < 16; ++i) {
        float4 a = p[lane * 16 + i];
        wi[4 * i] = a.x; wi[4 * i + 1] = a.y; wi[4 * i + 2] = a.z; wi[4 * i + 3] = a.w;
        float4 c = p[(64 + lane) * 16 + i];
        wf[4 * i] = c.x; wf[4 * i + 1] = c.y; wf[4 * i + 2] = c.z; wf[4 * i + 3] = c.w;
        float4 d = p[(128 + lane) * 16 + i];
        wg[4 * i] = d.x; wg[4 * i + 1] = d.y; wg[4 * i + 2] = d.z; wg[4 * i + 3] = d.w;
        float4 e = p[(192 + lane) * 16 + i];
        wo[4 * i] = e.x; wo[4 * i + 1] = e.y; wo[4 * i + 2] = e.z; wo[4 * i + 3] = e.w;
      }
    }
    const float m2 = m2g[b * HH + lane];
    float* ob = out + (size_t)b * TT * HH;

    float h2 = 0.f, c2 = 0.f;
    for (int s = 0; s < TT; ++s) {
      WAIT_GE(f_w1, s + 1);
      float axi = a2xbuf[s & 3][lane];
      float axf = a2xbuf[s & 3][64 + lane];
      float axg = a2xbuf[s & 3][128 + lane];
      float axo = a2xbuf[s & 3][192 + lane];

      float ai = axi, af = axf, ag = axg, ao = axo;
#pragma unroll
      for (int k = 0; k < HH; ++k) {
        float hk = bcast(h2, k);
        ai = fmaf(hk, wi[k], ai);
        af = fmaf(hk, wf[k], af);
        ag = fmaf(hk, wg[k], ag);
        ao = fmaf(hk, wo[k], ao);
      }
      c2 = sigm(af) * c2 + sigm(ai) * tanh_f(ag);
      h2 = sigm(ao) * tanh_f(c2);
      ob[(size_t)s * HH + lane] = fmaxf(h2 * m2, 0.f);
      PUBLISH(f_w2, s + 1);
    }
  }
#undef WAIT_GE
#undef PUBLISH
}

extern "C" void kernel_launch(void* const* d_in, const int* in_sizes, int n_in,
                              void* d_out, int out_size, void* d_ws, size_t ws_size,
                              hipStream_t stream) {
  (void)in_sizes; (void)n_in; (void)out_size; (void)ws_size;
  const float* x     = (const float*)d_in[0];
  const float* W_ih1 = (const float*)d_in[1];
  const float* W_hh1 = (const float*)d_in[2];
  const float* b_ih1 = (const float*)d_in[3];
  const float* b_hh1 = (const float*)d_in[4];
  const float* W_ih2 = (const float*)d_in[5];
  const float* W_hh2 = (const float*)d_in[6];
  const float* b_ih2 = (const float*)d_in[7];
  const float* b_hh2 = (const float*)d_in[8];
  const float* mask1 = (const float*)d_in[9];
  const float* mask2 = (const float*)d_in[10];
  float* out = (float*)d_out;

  float* xg1 = (float*)d_ws;  // B*T*4H fp32 = 134,217,728 bytes

  xgemm<<<dim3(BB * TT / 256), dim3(128), 0, stream>>>(x, W_ih1, b_ih1, b_hh1, xg1);
  lstm2<<<dim3(BB), dim3(256), 0, stream>>>(xg1, W_hh1, W_ih2, W_hh2, b_ih2, b_hh2,
                                            mask1, mask2, out);
}

// Round 4
// 2529.277 us; speedup vs baseline: 1.4939x; 1.0996x over previous
//
#include <hip/hip_runtime.h>
#include <hip/hip_bf16.h>

// Problem constants: B=64, T=2048, IN_F=128, H1=OUT_F=64, 4H=256
#define BB 64
#define TT 2048
#define INF 128
#define HH 64
#define GG 256  // 4*H

__device__ __forceinline__ float sigm(float x) { return 1.0f / (1.0f + __expf(-x)); }
__device__ __forceinline__ float tanh_f(float x) {
  float e = __expf(2.0f * x);
  return 1.0f - 2.0f / (e + 1.0f);
}
// Wave-uniform broadcast of lane l's value via v_readlane (SGPR path, no LDS).
__device__ __forceinline__ float bcast(float v, int l) {
  return __uint_as_float(__builtin_amdgcn_readlane(__float_as_uint(v), l));
}

// ---------------------------------------------------------------------------
// All hot loops are SOURCE-unrolled via macros: SROA runs before loop
// unrolling, so any variable array index sends the array to scratch (round
// 1-3: VGPR_Count 120/200/144 == spills). Literal indices -> constant GEPs
// -> arrays promoted to VGPRs.
// ---------------------------------------------------------------------------

// ---------------------------------------------------------------------------
// Kernel 1: xg1[m][n] = X[m,:].W_ih1[n,:] + b_ih1[n] + b_hh1[n]
// M=131072, N=256, K=128. Thread t owns W rows {t,128+t} in 256 VGPRs;
// x row lane-distributed (float2/lane), broadcast via readlane.
// 512 blocks x 128 threads.
// ---------------------------------------------------------------------------
#define XWL1(I)                                                   \
  { float4 a = Wp[t * 32 + (I)];                                  \
    w0[4*(I)] = a.x; w0[4*(I)+1] = a.y; w0[4*(I)+2] = a.z; w0[4*(I)+3] = a.w; \
    float4 b = Wp[(128 + t) * 32 + (I)];                          \
    w1[4*(I)] = b.x; w1[4*(I)+1] = b.y; w1[4*(I)+2] = b.z; w1[4*(I)+3] = b.w; }
#define XWL4(I) XWL1(I) XWL1((I)+1) XWL1((I)+2) XWL1((I)+3)
#define XWLOAD XWL4(0) XWL4(4) XWL4(8) XWL4(12) XWL4(16) XWL4(20) XWL4(24) XWL4(28)

#define XD1(L)                                                    \
  { float xa = bcast(curx, (L)); float xb = bcast(cury, (L));     \
    a0e = fmaf(xa, w0[2*(L)],   a0e); a0o = fmaf(xb, w0[2*(L)+1], a0o); \
    a1e = fmaf(xa, w1[2*(L)],   a1e); a1o = fmaf(xb, w1[2*(L)+1], a1o); }
#define XD8(L) XD1(L) XD1((L)+1) XD1((L)+2) XD1((L)+3) XD1((L)+4) XD1((L)+5) XD1((L)+6) XD1((L)+7)
#define XDOT64 XD8(0) XD8(8) XD8(16) XD8(24) XD8(32) XD8(40) XD8(48) XD8(56)

__global__ __launch_bounds__(128, 1) void xgemm(const float* __restrict__ X,
                                                const float* __restrict__ W,
                                                const float* __restrict__ bi,
                                                const float* __restrict__ bh,
                                                float* __restrict__ XG) {
  const int t = threadIdx.x;            // 0..127
  const int lane = t & 63;
  const long m0 = (long)blockIdx.x * 256;

  float w0[INF], w1[INF];
  const float4* Wp = (const float4*)W;
  XWLOAD
  const float bias0 = bi[t] + bh[t];
  const float bias1 = bi[128 + t] + bh[128 + t];

  const float2* Xp = (const float2*)X;  // lane l holds k=2l,2l+1
  float2 cur = Xp[(size_t)m0 * 64 + lane];
  float2 nx1 = Xp[(size_t)(m0 + 1) * 64 + lane];

  for (int mi = 0; mi < 256; ++mi) {
    const long m = m0 + mi;
    float2 nx2 = make_float2(0.f, 0.f);
    if (mi + 2 < 256) nx2 = Xp[(size_t)(m + 2) * 64 + lane];

    const float curx = cur.x, cury = cur.y;
    float a0e = bias0, a0o = 0.f, a1e = bias1, a1o = 0.f;  // 4 indep chains
    XDOT64
    XG[(size_t)m * GG + t] = a0e + a0o;
    XG[(size_t)m * GG + 128 + t] = a1e + a1o;
    cur = nx1; nx1 = nx2;
  }
}

// ---------------------------------------------------------------------------
// Kernel 2: barrier-free wave-specialized LSTM pipeline (validated r3).
//   W0: layer-1 recurrence -> x2 ring.  W1: Wih2.x2 -> a2x ring.
//   W2: Whh2.h2 (computed BEFORE the ring wait: off critical path) + update.
// Sync: monotonic LDS counters, volatile spin, lgkmcnt(0) before publish.
// ---------------------------------------------------------------------------
#define WL1(I)                                                                  \
  { float4 a = p[lane * 16 + (I)];                                              \
    wi[4*(I)] = a.x; wi[4*(I)+1] = a.y; wi[4*(I)+2] = a.z; wi[4*(I)+3] = a.w;   \
    float4 c = p[(64 + lane) * 16 + (I)];                                       \
    wf[4*(I)] = c.x; wf[4*(I)+1] = c.y; wf[4*(I)+2] = c.z; wf[4*(I)+3] = c.w;   \
    float4 d = p[(128 + lane) * 16 + (I)];                                      \
    wg[4*(I)] = d.x; wg[4*(I)+1] = d.y; wg[4*(I)+2] = d.z; wg[4*(I)+3] = d.w;   \
    float4 e = p[(192 + lane) * 16 + (I)];                                      \
    wo[4*(I)] = e.x; wo[4*(I)+1] = e.y; wo[4*(I)+2] = e.z; wo[4*(I)+3] = e.w; }
#define WL4(I) WL1(I) WL1((I)+1) WL1((I)+2) WL1((I)+3)
#define WLOAD WL4(0) WL4(4) WL4(8) WL4(12)

#define D1(K)                                              \
  { float hk = bcast(hv, (K));                             \
    ai = fmaf(hk, wi[(K)], ai); af = fmaf(hk, wf[(K)], af);\
    ag = fmaf(hk, wg[(K)], ag); ao = fmaf(hk, wo[(K)], ao); }
#define D8(K) D1(K) D1((K)+1) D1((K)+2) D1((K)+3) D1((K)+4) D1((K)+5) D1((K)+6) D1((K)+7)
#define DOT64 D8(0) D8(8) D8(16) D8(24) D8(32) D8(40) D8(48) D8(56)

__global__ __launch_bounds__(256, 1) void lstm2(const float* __restrict__ XG,
                                                const float* __restrict__ Whh1,
                                                const float* __restrict__ Wih2,
                                                const float* __restrict__ Whh2,
                                                const float* __restrict__ bi2,
                                                const float* __restrict__ bh2,
                                                const float* __restrict__ m1g,
                                                const float* __restrict__ m2g,
                                                float* __restrict__ out) {
  const int b = blockIdx.x;
  const int wid = threadIdx.x >> 6;
  const int lane = threadIdx.x & 63;

  __shared__ int f_w0, f_w1, f_w2;                  // steps completed per stage
  __shared__ __align__(16) float x2buf[4][HH];      // W0 -> W1 ring
  __shared__ __align__(16) float a2xbuf[4][GG];     // W1 -> W2 ring

  if (threadIdx.x == 0) { f_w0 = 0; f_w1 = 0; f_w2 = 0; }
  __syncthreads();  // one-time
  if (wid == 3) return;

#define WAIT_GE(flag, tgt)                                   \
  do {                                                       \
    while (*(volatile int*)&(flag) < (tgt)) {}               \
    asm volatile("" ::: "memory");                           \
  } while (0)
#define PUBLISH(flag, val)                                   \
  do {                                                       \
    asm volatile("s_waitcnt lgkmcnt(0)" ::: "memory");       \
    if (lane == 0) *(volatile int*)&(flag) = (val);          \
  } while (0)

  if (wid == 0) {
    // ---- stage 0: layer-1 recurrence ----
    float wi[HH], wf[HH], wg[HH], wo[HH];
    const float4* p = (const float4*)Whh1;
    WLOAD
    const float m1 = m1g[b * HH + lane];
    const float* xgp = XG + (size_t)b * TT * GG;

    float cur0 = xgp[lane], cur1 = xgp[64 + lane], cur2 = xgp[128 + lane], cur3 = xgp[192 + lane];
    float n10 = xgp[GG + lane], n11 = xgp[GG + 64 + lane], n12 = xgp[GG + 128 + lane], n13 = xgp[GG + 192 + lane];

    float h1 = 0.f, c1 = 0.f;
    for (int s = 0; s < TT; ++s) {
      float n20 = 0.f, n21 = 0.f, n22 = 0.f, n23 = 0.f;
      if (s + 2 < TT) {
        const float* q = xgp + (size_t)(s + 2) * GG;
        n20 = q[lane]; n21 = q[64 + lane]; n22 = q[128 + lane]; n23 = q[192 + lane];
      }

      const float hv = h1;
      float ai = cur0, af = cur1, ag = cur2, ao = cur3;
      DOT64
      c1 = sigm(af) * c1 + sigm(ai) * tanh_f(ag);
      h1 = sigm(ao) * tanh_f(c1);

      WAIT_GE(f_w1, s - 3);                 // ring slot free?
      x2buf[s & 3][lane] = h1 * m1;
      PUBLISH(f_w0, s + 1);

      cur0 = n10; cur1 = n11; cur2 = n12; cur3 = n13;
      n10 = n20; n11 = n21; n12 = n22; n13 = n23;
    }
  } else if (wid == 1) {
    // ---- stage 1: layer-2 input dot ----
    float wi[HH], wf[HH], wg[HH], wo[HH];
    const float4* p = (const float4*)Wih2;
    WLOAD
    const float bi_i = bi2[lane] + bh2[lane];
    const float bi_f = bi2[64 + lane] + bh2[64 + lane];
    const float bi_g = bi2[128 + lane] + bh2[128 + lane];
    const float bi_o = bi2[192 + lane] + bh2[192 + lane];

    for (int s = 0; s < TT; ++s) {
      WAIT_GE(f_w0, s + 1);
      const float hv = x2buf[s & 3][lane];

      float ai = bi_i, af = bi_f, ag = bi_g, ao = bi_o;
      DOT64
      WAIT_GE(f_w2, s - 3);                 // ring slot free?
      a2xbuf[s & 3][lane] = ai;
      a2xbuf[s & 3][64 + lane] = af;
      a2xbuf[s & 3][128 + lane] = ag;
      a2xbuf[s & 3][192 + lane] = ao;
      PUBLISH(f_w1, s + 1);
    }
  } else {
    // ---- stage 2: layer-2 recurrent dot + update + store ----
    float wi[HH], wf[HH], wg[HH], wo[HH];
    const float4* p = (const float4*)Whh2;
    WLOAD
    const float m2 = m2g[b * HH + lane];
    float* ob = out + (size_t)b * TT * HH;

    float h2 = 0.f, c2 = 0.f;
    for (int s = 0; s < TT; ++s) {
      // Whh2 . h2(s-1): no dependence on W1 -> compute BEFORE the ring wait.
      const float hv = h2;
      float ai = 0.f, af = 0.f, ag = 0.f, ao = 0.f;
      DOT64

      WAIT_GE(f_w1, s + 1);
      ai += a2xbuf[s & 3][lane];
      af += a2xbuf[s & 3][64 + lane];
      ag += a2xbuf[s & 3][128 + lane];
      ao += a2xbuf[s & 3][192 + lane];

      c2 = sigm(af) * c2 + sigm(ai) * tanh_f(ag);
      h2 = sigm(ao) * tanh_f(c2);
      PUBLISH(f_w2, s + 1);
      ob[(size_t)s * HH + lane] = fmaxf(h2 * m2, 0.f);
    }
  }
#undef WAIT_GE
#undef PUBLISH
}

extern "C" void kernel_launch(void* const* d_in, const int* in_sizes, int n_in,
                              void* d_out, int out_size, void* d_ws, size_t ws_size,
                              hipStream_t stream) {
  (void)in_sizes; (void)n_in; (void)out_size; (void)ws_size;
  const float* x     = (const float*)d_in[0];
  const float* W_ih1 = (const float*)d_in[1];
  const float* W_hh1 = (const float*)d_in[2];
  const float* b_ih1 = (const float*)d_in[3];
  const float* b_hh1 = (const float*)d_in[4];
  const float* W_ih2 = (const float*)d_in[5];
  const float* W_hh2 = (const float*)d_in[6];
  const float* b_ih2 = (const float*)d_in[7];
  const float* b_hh2 = (const float*)d_in[8];
  const float* mask1 = (const float*)d_in[9];
  const float* mask2 = (const float*)d_in[10];
  float* out = (float*)d_out;

  float* xg1 = (float*)d_ws;  // B*T*4H fp32 = 134,217,728 bytes

  xgemm<<<dim3(BB * TT / 256), dim3(128), 0, stream>>>(x, W_ih1, b_ih1, b_hh1, xg1);
  lstm2<<<dim3(BB), dim3(256), 0, stream>>>(xg1, W_hh1, W_ih2, W_hh2, b_ih2, b_hh2,
                                            mask1, mask2, out);
}